// Round 9
// baseline (1311.743 us; speedup 1.0000x reference)
//
#include <hip/hip_runtime.h>
#include <hip/hip_bf16.h>
#include <stdint.h>

#define Bb 4
#define Dd 128
#define Nn 16384
#define Ee 65536
#define GRIDP 768          // persistent blocks: 3/CU x 256 CU
#define NTILES 4096        // (Ee/64) * Bb tiles per side

typedef __attribute__((ext_vector_type(4))) float f32x4;
typedef __attribute__((ext_vector_type(8))) short s16x8;

__device__ __forceinline__ unsigned short f2bf(float f) {
  union { float f; unsigned int u; } v; v.f = f;
  unsigned int r = v.u + 0x7fffu + ((v.u >> 16) & 1u);
  return (unsigned short)(r >> 16);
}

// ---- fold BN into weights, convert to bf16 ----
__global__ void prep_weights(const float* __restrict__ w1, const float* __restrict__ b1,
                             const float* __restrict__ g, const float* __restrict__ beta,
                             const float* __restrict__ mu, const float* __restrict__ var,
                             const float* __restrict__ w2,
                             unsigned short* __restrict__ W1s, unsigned short* __restrict__ W2s,
                             float* __restrict__ c1) {
  int i = blockIdx.x * 256 + threadIdx.x;
  if (i < 256 * 384) {
    int o = i / 384;
    float scale = g[o] * rsqrtf(var[o] + 1e-5f);
    W1s[i] = f2bf(w1[i] * scale);
  }
  if (i < 128 * 256) W2s[i] = f2bf(w2[i]);
  if (i < 256) {
    float scale = g[i] * rsqrtf(var[i] + 1e-5f);
    c1[i] = b1[i] * scale + beta[i] - mu[i] * scale;
  }
}

// ---- transpose one side: ldesc [B][D][N] f32 -> [B][N][D] bf16 ----
__global__ void transpose_side(const float* __restrict__ src, unsigned short* __restrict__ dst) {
  __shared__ float tile[32][33];
  int n0 = blockIdx.x * 32;
  int d0 = blockIdx.y * 32;
  int b = blockIdx.z;
  const float* s = src + (size_t)b * Dd * Nn;
  unsigned short* d = dst + (size_t)b * Nn * Dd;
  int tx = threadIdx.x, ty = threadIdx.y;
#pragma unroll
  for (int i = 0; i < 4; ++i)
    tile[ty + i * 8][tx] = s[(size_t)(d0 + ty + i * 8) * Nn + n0 + tx];
  __syncthreads();
#pragma unroll
  for (int i = 0; i < 4; ++i) {
    int r = ty + i * 8;
    d[(size_t)(n0 + r) * Dd + d0 + tx] = f2bf(tile[tx][r]);
  }
}

// ---- CSR build: histogram ----
__global__ void hist_kernel(const int* __restrict__ idx0, const int* __restrict__ idx1,
                            int* __restrict__ hist) {
  int i = blockIdx.x * 256 + threadIdx.x;  // 0 .. 2*B*E-1
  int sb = i >> 16;                        // side*4 + b
  int e = i & 65535;
  const int* jx = (sb >= 4) ? idx1 : idx0;
  int n = jx[(size_t)(sb & 3) * Ee + e];
  atomicAdd(&hist[sb * Nn + n], 1);
}

// ---- CSR build: per-sb exclusive scan of 16384 bins ----
__global__ __launch_bounds__(1024) void scan_kernel(const int* __restrict__ hist,
                                                    int* __restrict__ offs,
                                                    int* __restrict__ cursor) {
  __shared__ int part[1024];
  int sb = blockIdx.x, t = threadIdx.x;
  const int* h = hist + sb * Nn;
  int base = t * 16;
  int v[16];
  int local = 0;
#pragma unroll
  for (int i = 0; i < 16; ++i) { v[i] = local; local += h[base + i]; }
  part[t] = local;
  __syncthreads();
  for (int d = 1; d < 1024; d <<= 1) {
    int y = (t >= d) ? part[t - d] : 0;
    __syncthreads();
    part[t] += y;
    __syncthreads();
  }
  int excl = part[t] - local;
#pragma unroll
  for (int i = 0; i < 16; ++i) {
    int o = excl + v[i];
    offs[sb * Nn + base + i] = o;
    cursor[sb * Nn + base + i] = o;
  }
}

// ---- CSR build: fill entry lists ----
__global__ void fill_kernel(const int* __restrict__ idx0, const int* __restrict__ idx1,
                            int* __restrict__ cursor, int* __restrict__ elist) {
  int i = blockIdx.x * 256 + threadIdx.x;
  int sb = i >> 16;
  int e = i & 65535;
  const int* jx = (sb >= 4) ? idx1 : idx0;
  int n = jx[(size_t)(sb & 3) * Ee + e];
  int pos = atomicAdd(&cursor[sb * Nn + n], 1);
  elist[(size_t)sb * Ee + pos] = e;
}

// LDS: 64 columns x 256 bf16; XOR-swizzled 16B units: unit u of column c at u ^ (c&7).
__device__ __forceinline__ int swz(int col, int unit) { return col * 32 + (unit ^ (col & 7)); }

// stage tile g_'s inputs into registers (issue loads; waits land at WRITE_LDS)
#define STAGE_REGS(g_)                                                          \
  do {                                                                          \
    int bn_ = (g_) >> 10, e0n_ = ((g_) & 1023) << 6;                            \
    int i0_ = jx[(size_t)bn_ * Ee + e0n_ + j4];                                 \
    const uint4* s0_ = (const uint4*)(ldescT + ((size_t)bn_ * Nn + i0_) * Dd + p4 * 32); \
    _Pragma("unroll") for (int q = 0; q < 4; ++q) dreg[q] = s0_[q];             \
    const float* es_ = enc + ((size_t)bn_ * Dd + dg * 32) * Ee + e0n_ + j63;    \
    _Pragma("unroll") for (int d_ = 0; d_ < 32; ++d_) ereg[d_] = es_[(size_t)d_ * Ee]; \
  } while (0)

// pack staged regs -> swizzled LDS X tile
#define WRITE_LDS()                                                             \
  do {                                                                          \
    _Pragma("unroll") for (int q = 0; q < 4; ++q)                               \
      smem4[swz(j4, p4 * 4 + q)] = dreg[q];                                     \
    _Pragma("unroll") for (int i8 = 0; i8 < 4; ++i8) {                          \
      uint4 pk_;                                                                \
      unsigned int* pw_ = (unsigned int*)&pk_;                                  \
      _Pragma("unroll") for (int d2 = 0; d2 < 4; ++d2)                          \
        pw_[d2] = (unsigned int)f2bf(ereg[i8 * 8 + d2 * 2]) |                   \
                  ((unsigned int)f2bf(ereg[i8 * 8 + d2 * 2 + 1]) << 16);        \
      smem4[swz(j63, 16 + dg * 4 + i8)] = pk_;                                  \
    }                                                                           \
  } while (0)

// persistent fused MLP: one side per launch, blocks loop over tiles with
// register-staged prefetch of the next tile hidden under the current GEMMs.
__global__ __launch_bounds__(256, 3) void fused_line_mlp(
    const unsigned short* __restrict__ ldescT, const float* __restrict__ enc,
    const int* __restrict__ jx,
    const unsigned short* __restrict__ W1s, const unsigned short* __restrict__ W2s,
    const float* __restrict__ c1, const float* __restrict__ b2,
    unsigned short* __restrict__ U) {
  __shared__ uint4 smem4[64 * 32];  // 32768 B: X tile, aliased as H tile
  unsigned short* sm = (unsigned short*)smem4;

  const int t = threadIdx.x;
  const int w = t >> 6;          // wave 0..3
  const int lr = t & 15;         // row/col within 16-tile
  const int lk = (t & 63) >> 4;  // k-group 0..3
  const int j4 = t >> 2, p4 = t & 3;   // desc staging identity
  const int j63 = t & 63, dg = t >> 6; // enc staging identity

  uint4 dreg[4];
  float ereg[32];

  int g = blockIdx.x;
  STAGE_REGS(g);
  WRITE_LDS();
  __syncthreads();

  while (true) {
    const int bcur = g >> 10;
    const int e0c = (g & 1023) << 6;
    const int gn = g + GRIDP;
    const bool have_next = (gn < NTILES);
    if (have_next) STAGE_REGS(gn);   // issue next tile's loads, no wait

    // ---- GEMM1: H[256,64] = W1s[256,384] * X[384,64] ----
    // ks 0..3 own desc; 4..7 pair desc (col c^1); 8..11 enc.
    f32x4 acc[4][4] = {};
#pragma unroll
    for (int ks = 0; ks < 12; ++ks) {
      s16x8 bfrag[4];
#pragma unroll
      for (int ct = 0; ct < 4; ++ct) {
        int c = ct * 16 + lr;
        int ce, bu;
        if (ks < 4)      { ce = c;     bu = ks * 4 + lk; }
        else if (ks < 8) { ce = c ^ 1; bu = (ks - 4) * 4 + lk; }
        else             { ce = c;     bu = 16 + (ks - 8) * 4 + lk; }
        bfrag[ct] = *(const s16x8*)&sm[swz(ce, bu) * 8];
      }
#pragma unroll
      for (int rt = 0; rt < 4; ++rt) {
        const s16x8 afrag = *(const s16x8*)&W1s[(size_t)(w * 64 + rt * 16 + lr) * 384 + ks * 32 + lk * 8];
#pragma unroll
        for (int ct = 0; ct < 4; ++ct)
          acc[rt][ct] = __builtin_amdgcn_mfma_f32_16x16x32_bf16(afrag, bfrag[ct], acc[rt][ct], 0, 0, 0);
      }
    }
    __syncthreads();  // X reads done -> reuse as H

    // ---- bias + ReLU -> H bf16 in LDS (swizzled, rows = GEMM2 k) ----
#pragma unroll
    for (int rt = 0; rt < 4; ++rt) {
      int rowbase = w * 64 + rt * 16 + lk * 4;
      int unit = rowbase >> 3;
      int inner = rowbase & 7;  // 0 or 4
      float c1v[4];
#pragma unroll
      for (int r = 0; r < 4; ++r) c1v[r] = c1[rowbase + r];
#pragma unroll
      for (int ct = 0; ct < 4; ++ct) {
        int col = ct * 16 + lr;
        float v0 = fmaxf(acc[rt][ct][0] + c1v[0], 0.f);
        float v1 = fmaxf(acc[rt][ct][1] + c1v[1], 0.f);
        float v2 = fmaxf(acc[rt][ct][2] + c1v[2], 0.f);
        float v3 = fmaxf(acc[rt][ct][3] + c1v[3], 0.f);
        uint2 pk;
        pk.x = (unsigned int)f2bf(v0) | ((unsigned int)f2bf(v1) << 16);
        pk.y = (unsigned int)f2bf(v2) | ((unsigned int)f2bf(v3) << 16);
        *(uint2*)&sm[swz(col, unit) * 8 + inner] = pk;
      }
    }
    __syncthreads();

    // ---- GEMM2: Uo[128,64] = W2s[128,256] * H[256,64] ----
    f32x4 acc2[2][4] = {};
#pragma unroll
    for (int ks = 0; ks < 8; ++ks) {
      s16x8 bfrag[4];
#pragma unroll
      for (int ct = 0; ct < 4; ++ct) {
        int c = ct * 16 + lr;
        bfrag[ct] = *(const s16x8*)&sm[swz(c, ks * 4 + lk) * 8];
      }
#pragma unroll
      for (int rt = 0; rt < 2; ++rt) {
        const s16x8 afrag = *(const s16x8*)&W2s[(size_t)(w * 32 + rt * 16 + lr) * 256 + ks * 32 + lk * 8];
#pragma unroll
        for (int ct = 0; ct < 4; ++ct)
          acc2[rt][ct] = __builtin_amdgcn_mfma_f32_16x16x32_bf16(afrag, bfrag[ct], acc2[rt][ct], 0, 0, 0);
      }
    }

    // ---- epilogue: + b2 -> bf16 U[b][e][d] ----
#pragma unroll
    for (int rt = 0; rt < 2; ++rt) {
      int rowbase = w * 32 + rt * 16 + lk * 4;
      float b2v[4];
#pragma unroll
      for (int r = 0; r < 4; ++r) b2v[r] = b2[rowbase + r];
#pragma unroll
      for (int ct = 0; ct < 4; ++ct) {
        int col = ct * 16 + lr;
        float v0 = acc2[rt][ct][0] + b2v[0];
        float v1 = acc2[rt][ct][1] + b2v[1];
        float v2 = acc2[rt][ct][2] + b2v[2];
        float v3 = acc2[rt][ct][3] + b2v[3];
        uint2 pk;
        pk.x = (unsigned int)f2bf(v0) | ((unsigned int)f2bf(v1) << 16);
        pk.y = (unsigned int)f2bf(v2) | ((unsigned int)f2bf(v3) << 16);
        *(uint2*)&U[(((size_t)bcur * Ee + e0c + col) << 7) + rowbase] = pk;
      }
    }

    if (!have_next) break;
    __syncthreads();   // H reads done -> safe to overwrite with next X
    WRITE_LDS();       // waits on staged regs here (hidden under the GEMMs)
    __syncthreads();
    g = gn;
  }
}

// ---- scatter-mean + residual + transpose (R3-proven serial-chain version) ----
// grid (Nn/64, Bb), block 256. Wave w handles junctions n0+w*16 .. +15.
__global__ __launch_bounds__(256) void scatter_finalize(
    const unsigned short* __restrict__ U, const int* __restrict__ elist_s,
    const int* __restrict__ offs_s, const float* __restrict__ ldesc_s,
    float* __restrict__ out_s) {
  __shared__ float lsum[64][129];
  const int b = blockIdx.y;
  const int n0 = blockIdx.x * 64;
  const int t = threadIdx.x;
  const int w = t >> 6, lane = t & 63;
  const unsigned int* Uu = (const unsigned int*)U;  // row = 64 uints (128 bf16)

#pragma unroll 1
  for (int q = 0; q < 16; ++q) {
    int jj = w * 16 + q;
    int n = n0 + jj;
    int s = offs_s[b * Nn + n];
    int e_end = (n == Nn - 1) ? Ee : offs_s[b * Nn + n + 1];
    float s0 = 0.f, s1 = 0.f;
    for (int k = s; k < e_end; ++k) {
      int e = elist_s[(size_t)b * Ee + k];
      unsigned int p = Uu[(((size_t)b * Ee + e) << 6) + lane];
      union { unsigned int u; float f; } lo, hi;
      lo.u = p << 16;
      hi.u = p & 0xffff0000u;
      s0 += lo.f;
      s1 += hi.f;
    }
    float inv = (e_end > s) ? 1.0f / (float)(e_end - s) : 0.0f;
    lsum[jj][lane * 2] = s0 * inv;
    lsum[jj][lane * 2 + 1] = s1 * inv;
  }
  __syncthreads();

  int nloc = t & 63;
  int dbase = (t >> 6) * 32;
#pragma unroll
  for (int i = 0; i < 32; ++i) {
    int d = dbase + i;
    size_t o = (size_t)(b * Dd + d) * Nn + n0 + nloc;
    out_s[o] = ldesc_s[o] + lsum[nloc][d];
  }
}

extern "C" void kernel_launch(void* const* d_in, const int* in_sizes, int n_in,
                              void* d_out, int out_size, void* d_ws, size_t ws_size,
                              hipStream_t stream) {
  const float* ldesc0 = (const float*)d_in[0];
  const float* ldesc1 = (const float*)d_in[1];
  const float* enc0   = (const float*)d_in[2];
  const float* enc1   = (const float*)d_in[3];
  const int*   idx0   = (const int*)d_in[4];
  const int*   idx1   = (const int*)d_in[5];
  const float* w1     = (const float*)d_in[6];
  const float* b1     = (const float*)d_in[7];
  const float* g      = (const float*)d_in[8];
  const float* beta   = (const float*)d_in[9];
  const float* mu     = (const float*)d_in[10];
  const float* var    = (const float*)d_in[11];
  const float* w2     = (const float*)d_in[12];
  const float* b2     = (const float*)d_in[13];
  float* out = (float*)d_out;

  char* ws = (char*)d_ws;
  size_t off = 0;
  unsigned short* t   = (unsigned short*)(ws + off); off += (size_t)Bb * Nn * Dd * 2;
  unsigned short* W1s = (unsigned short*)(ws + off); off += 256 * 384 * 2;
  unsigned short* W2s = (unsigned short*)(ws + off); off += 128 * 256 * 2;
  float* c1   = (float*)(ws + off); off += 256 * 4;
  int* hist   = (int*)(ws + off); off += (size_t)8 * Nn * 4;
  int* offs   = (int*)(ws + off); off += (size_t)8 * Nn * 4;
  int* cursor = (int*)(ws + off); off += (size_t)8 * Nn * 4;
  int* elist  = (int*)(ws + off); off += (size_t)8 * Ee * 4;
  unsigned short* U = (unsigned short*)(ws + off); off += (size_t)Bb * Ee * Dd * 2;

  hipMemsetAsync(hist, 0, (size_t)8 * Nn * 4, stream);
  prep_weights<<<384, 256, 0, stream>>>(w1, b1, g, beta, mu, var, w2, W1s, W2s, c1);
  hist_kernel<<<2048, 256, 0, stream>>>(idx0, idx1, hist);
  scan_kernel<<<8, 1024, 0, stream>>>(hist, offs, cursor);
  fill_kernel<<<2048, 256, 0, stream>>>(idx0, idx1, cursor, elist);

  for (int side = 0; side < 2; ++side) {
    const float* ldesc_s = side ? ldesc1 : ldesc0;
    const float* enc_s = side ? enc1 : enc0;
    const int* jx = side ? idx1 : idx0;
    transpose_side<<<dim3(Nn / 32, Dd / 32, Bb), dim3(32, 8), 0, stream>>>(ldesc_s, t);
    fused_line_mlp<<<GRIDP, 256, 0, stream>>>(t, enc_s, jx, W1s, W2s, c1, b2, U);
    scatter_finalize<<<dim3(Nn / 64, Bb), 256, 0, stream>>>(
        U, elist + (size_t)side * 4 * Ee, offs + (size_t)side * 4 * Nn,
        ldesc_s, out + (size_t)side * Bb * Dd * Nn);
  }
}

// Round 10
// 450.967 us; speedup vs baseline: 2.9087x; 2.9087x over previous
//
#include <hip/hip_runtime.h>
#include <hip/hip_bf16.h>
#include <stdint.h>

#define Bb 4
#define Dd 128
#define Nn 16384
#define Ee 65536
#define NTB 16   // tiles per block in the persistent fused kernel

typedef __attribute__((ext_vector_type(4))) float f32x4;
typedef __attribute__((ext_vector_type(8))) short s16x8;

__device__ __forceinline__ unsigned short f2bf(float f) {
  union { float f; unsigned int u; } v; v.f = f;
  unsigned int r = v.u + 0x7fffu + ((v.u >> 16) & 1u);
  return (unsigned short)(r >> 16);
}

// ---- fold BN into weights, convert to bf16 ----
__global__ void prep_weights(const float* __restrict__ w1, const float* __restrict__ b1,
                             const float* __restrict__ g, const float* __restrict__ beta,
                             const float* __restrict__ mu, const float* __restrict__ var,
                             const float* __restrict__ w2,
                             unsigned short* __restrict__ W1s, unsigned short* __restrict__ W2s,
                             float* __restrict__ c1) {
  int i = blockIdx.x * 256 + threadIdx.x;
  if (i < 256 * 384) {
    int o = i / 384;
    float scale = g[o] * rsqrtf(var[o] + 1e-5f);
    W1s[i] = f2bf(w1[i] * scale);
  }
  if (i < 128 * 256) W2s[i] = f2bf(w2[i]);
  if (i < 256) {
    float scale = g[i] * rsqrtf(var[i] + 1e-5f);
    c1[i] = b1[i] * scale + beta[i] - mu[i] * scale;
  }
}

// ---- transpose [128][ncols] f32 -> [ncols][128] bf16 (one batch slice per z) ----
__global__ void transpose_f2b(const float* __restrict__ src, unsigned short* __restrict__ dst,
                              int ncols) {
  __shared__ float tile[32][33];
  int n0 = blockIdx.x * 32;
  int d0 = blockIdx.y * 32;
  int b = blockIdx.z;
  const float* s = src + (size_t)b * Dd * ncols;
  unsigned short* d = dst + (size_t)b * ncols * Dd;
  int tx = threadIdx.x, ty = threadIdx.y;
#pragma unroll
  for (int i = 0; i < 4; ++i)
    tile[ty + i * 8][tx] = s[(size_t)(d0 + ty + i * 8) * ncols + n0 + tx];
  __syncthreads();
#pragma unroll
  for (int i = 0; i < 4; ++i) {
    int r = ty + i * 8;
    d[(size_t)(n0 + r) * Dd + d0 + tx] = f2bf(tile[tx][r]);
  }
}

// ---- CSR build: histogram ----
__global__ void hist_kernel(const int* __restrict__ idx0, const int* __restrict__ idx1,
                            int* __restrict__ hist) {
  int i = blockIdx.x * 256 + threadIdx.x;  // 0 .. 2*B*E-1
  int sb = i >> 16;                        // side*4 + b
  int e = i & 65535;
  const int* jx = (sb >= 4) ? idx1 : idx0;
  int n = jx[(size_t)(sb & 3) * Ee + e];
  atomicAdd(&hist[sb * Nn + n], 1);
}

// ---- CSR build: per-sb exclusive scan of 16384 bins ----
__global__ __launch_bounds__(1024) void scan_kernel(const int* __restrict__ hist,
                                                    int* __restrict__ offs,
                                                    int* __restrict__ cursor) {
  __shared__ int part[1024];
  int sb = blockIdx.x, t = threadIdx.x;
  const int* h = hist + sb * Nn;
  int base = t * 16;
  int v[16];
  int local = 0;
#pragma unroll
  for (int i = 0; i < 16; ++i) { v[i] = local; local += h[base + i]; }
  part[t] = local;
  __syncthreads();
  for (int d = 1; d < 1024; d <<= 1) {
    int y = (t >= d) ? part[t - d] : 0;
    __syncthreads();
    part[t] += y;
    __syncthreads();
  }
  int excl = part[t] - local;
#pragma unroll
  for (int i = 0; i < 16; ++i) {
    int o = excl + v[i];
    offs[sb * Nn + base + i] = o;
    cursor[sb * Nn + base + i] = o;
  }
}

// ---- CSR build: fill entry lists ----
__global__ void fill_kernel(const int* __restrict__ idx0, const int* __restrict__ idx1,
                            int* __restrict__ cursor, int* __restrict__ elist) {
  int i = blockIdx.x * 256 + threadIdx.x;
  int sb = i >> 16;
  int e = i & 65535;
  const int* jx = (sb >= 4) ? idx1 : idx0;
  int n = jx[(size_t)(sb & 3) * Ee + e];
  int pos = atomicAdd(&cursor[sb * Nn + n], 1);
  elist[(size_t)sb * Ee + pos] = e;
}

// ======================= NEW persistent weight-stationary fused MLP ==========
// LDS: X dbuf 2 x 32KB  (per buf: desc plane 16KB + enc plane 16KB; col c at
// bytes c*256, 16 16B-units swizzled u^(c&7)) + H 32KB (col*512B, 32 units,
// unit = row>>3, swizzled ^(c&7)). Staged entirely by global_load_lds with
// pre-swizzled per-lane SOURCE addresses and linear LDS dest (rule 21).
#define STAGE(ti, buf)                                                          \
  do {                                                                          \
    int e0s_ = (tile0 + (ti)) * 64;                                             \
    unsigned char* xb_ = sm + (buf) * 32768;                                    \
    int cA_ = w * 8 + (lane >> 4);                                              \
    int cB_ = cA_ + 4;                                                          \
    int uA_ = (lane & 15) ^ (cA_ & 7);                                          \
    int uB_ = (lane & 15) ^ (cB_ & 7);                                          \
    int iA_ = jx[(size_t)bB * Ee + e0s_ + cA_];                                 \
    int iB_ = jx[(size_t)bB * Ee + e0s_ + cB_];                                 \
    __builtin_amdgcn_global_load_lds(                                           \
        (const __attribute__((address_space(1))) void*)(ldescT + ((size_t)bB * Nn + iA_) * 128 + uA_ * 8), \
        (__attribute__((address_space(3))) void*)(xb_ + (w * 8) * 256), 16, 0, 0); \
    __builtin_amdgcn_global_load_lds(                                           \
        (const __attribute__((address_space(1))) void*)(ldescT + ((size_t)bB * Nn + iB_) * 128 + uB_ * 8), \
        (__attribute__((address_space(3))) void*)(xb_ + (w * 8 + 4) * 256), 16, 0, 0); \
    __builtin_amdgcn_global_load_lds(                                           \
        (const __attribute__((address_space(1))) void*)(encT + ((size_t)bB * Ee + e0s_ + cA_) * 128 + uA_ * 8), \
        (__attribute__((address_space(3))) void*)(xb_ + 16384 + (w * 8) * 256), 16, 0, 0); \
    __builtin_amdgcn_global_load_lds(                                           \
        (const __attribute__((address_space(1))) void*)(encT + ((size_t)bB * Ee + e0s_ + cB_) * 128 + uB_ * 8), \
        (__attribute__((address_space(3))) void*)(xb_ + 16384 + (w * 8 + 4) * 256), 16, 0, 0); \
  } while (0)

__global__ __launch_bounds__(512, 2) void fused_mlp_ws(
    const unsigned short* __restrict__ ldescT,   // [B][N][128] bf16
    const unsigned short* __restrict__ encT,     // [B][E][128] bf16
    const int* __restrict__ jx,
    const unsigned short* __restrict__ W1s, const unsigned short* __restrict__ W2s,
    const float* __restrict__ c1, const float* __restrict__ b2,
    unsigned short* __restrict__ U) {
  __shared__ __align__(16) unsigned char sm[98304];  // 96 KB

  const int t = threadIdx.x;
  const int w = t >> 6;           // wave 0..7
  const int lane = t & 63;
  const int lr = t & 15;
  const int lk = (t & 63) >> 4;
  const int bB = blockIdx.x >> 6;            // batch
  const int tile0 = (blockIdx.x & 63) * NTB; // 64 blocks per batch, 16 tiles each

  // ---- stationary weights: W1 rows [w*32, w*32+32), W2 rows [w*16, w*16+16) ----
  s16x8 w1f[2][12];
#pragma unroll
  for (int rt = 0; rt < 2; ++rt)
#pragma unroll
    for (int ks = 0; ks < 12; ++ks)
      w1f[rt][ks] = *(const s16x8*)&W1s[(size_t)(w * 32 + rt * 16 + lr) * 384 + ks * 32 + lk * 8];
  s16x8 w2f[8];
#pragma unroll
  for (int ks = 0; ks < 8; ++ks)
    w2f[ks] = *(const s16x8*)&W2s[(size_t)(w * 16 + lr) * 256 + ks * 32 + lk * 8];
  float c1v[2][4], b2v[4];
#pragma unroll
  for (int rt = 0; rt < 2; ++rt)
#pragma unroll
    for (int r = 0; r < 4; ++r) c1v[rt][r] = c1[w * 32 + rt * 16 + lk * 4 + r];
#pragma unroll
  for (int r = 0; r < 4; ++r) b2v[r] = b2[w * 16 + lk * 4 + r];

  // ---- prologue: stage tiles 0 and 1 ----
  STAGE(0, 0);
  STAGE(1, 1);
  asm volatile("s_waitcnt vmcnt(4)" ::: "memory");  // X0 complete (X1 may fly)
  __builtin_amdgcn_s_barrier();
  __builtin_amdgcn_sched_barrier(0);

  unsigned short* hb = (unsigned short*)(sm + 65536);

#pragma unroll 1
  for (int i = 0; i < NTB; ++i) {
    const int p = i & 1;
    const unsigned short* xb = (const unsigned short*)(sm + p * 32768);
    const int e0c = (tile0 + i) * 64;

    // ---- GEMM1: H[256,64] = W1*X, weights in regs, X from LDS ----
    f32x4 acc[2][4] = {};
#pragma unroll
    for (int ks = 0; ks < 12; ++ks) {
      s16x8 bf[4];
#pragma unroll
      for (int ct = 0; ct < 4; ++ct) {
        int c = ct * 16 + lr;
        int off;
        if (ks < 4)      { off = c * 128 + (((ks * 4 + lk) ^ (c & 7)) * 8); }
        else if (ks < 8) { int c2 = c ^ 1; off = c2 * 128 + ((((ks - 4) * 4 + lk) ^ (c2 & 7)) * 8); }
        else             { off = 8192 + c * 128 + ((((ks - 8) * 4 + lk) ^ (c & 7)) * 8); }
        bf[ct] = *(const s16x8*)&xb[off];
      }
#pragma unroll
      for (int rt = 0; rt < 2; ++rt)
#pragma unroll
        for (int ct = 0; ct < 4; ++ct)
          acc[rt][ct] = __builtin_amdgcn_mfma_f32_16x16x32_bf16(w1f[rt][ks], bf[ct], acc[rt][ct], 0, 0, 0);
    }

    // ---- bias + ReLU -> H (swizzled) ----
#pragma unroll
    for (int rt = 0; rt < 2; ++rt) {
      int rowbase = w * 32 + rt * 16 + lk * 4;
      int unitr = rowbase >> 3, inner = rowbase & 7;  // inner 0 or 4
#pragma unroll
      for (int ct = 0; ct < 4; ++ct) {
        int col = ct * 16 + lr;
        float v0 = fmaxf(acc[rt][ct][0] + c1v[rt][0], 0.f);
        float v1 = fmaxf(acc[rt][ct][1] + c1v[rt][1], 0.f);
        float v2 = fmaxf(acc[rt][ct][2] + c1v[rt][2], 0.f);
        float v3 = fmaxf(acc[rt][ct][3] + c1v[rt][3], 0.f);
        uint2 pk;
        pk.x = (unsigned int)f2bf(v0) | ((unsigned int)f2bf(v1) << 16);
        pk.y = (unsigned int)f2bf(v2) | ((unsigned int)f2bf(v3) << 16);
        *(uint2*)&hb[col * 256 + ((unitr ^ (col & 7)) * 8) + inner] = pk;
      }
    }
    asm volatile("s_waitcnt lgkmcnt(0)" ::: "memory");
    __builtin_amdgcn_s_barrier();           // H visible; X[p] free
    __builtin_amdgcn_sched_barrier(0);

    // ---- issue async staging of tile i+2 into X[p] (counted, not drained) ----
    if (i + 2 < NTB) STAGE(i + 2, p);

    // ---- GEMM2: U[128,64] = W2*H ----
    f32x4 acc2[4] = {};
#pragma unroll
    for (int ks = 0; ks < 8; ++ks) {
      s16x8 bf[4];
#pragma unroll
      for (int ct = 0; ct < 4; ++ct) {
        int c = ct * 16 + lr;
        bf[ct] = *(const s16x8*)&hb[c * 256 + (((ks * 4 + lk) ^ (c & 7)) * 8)];
      }
#pragma unroll
      for (int ct = 0; ct < 4; ++ct)
        acc2[ct] = __builtin_amdgcn_mfma_f32_16x16x32_bf16(w2f[ks], bf[ct], acc2[ct], 0, 0, 0);
    }

    // ---- epilogue: + b2 -> bf16 U[b][e][d] ----
#pragma unroll
    for (int ct = 0; ct < 4; ++ct) {
      int col = ct * 16 + lr;
      float v0 = acc2[ct][0] + b2v[0];
      float v1 = acc2[ct][1] + b2v[1];
      float v2 = acc2[ct][2] + b2v[2];
      float v3 = acc2[ct][3] + b2v[3];
      uint2 pk;
      pk.x = (unsigned int)f2bf(v0) | ((unsigned int)f2bf(v1) << 16);
      pk.y = (unsigned int)f2bf(v2) | ((unsigned int)f2bf(v3) << 16);
      *(uint2*)&U[(((size_t)bB * Ee + e0c + col) << 7) + w * 16 + lk * 4] = pk;
    }

    if (i + 1 < NTB) {
      asm volatile("s_waitcnt lgkmcnt(0)" ::: "memory");
      asm volatile("s_waitcnt vmcnt(8)" ::: "memory");  // stage(i+1) landed; stage(i+2)+stores stay in flight
      __builtin_amdgcn_s_barrier();          // X[p^1] ready for all waves; H free
      __builtin_amdgcn_sched_barrier(0);
    }
  }
}

// ======================= fallback fused MLP (R4, ws-lean path) ===============
__device__ __forceinline__ int swz(int col, int unit) { return col * 32 + (unit ^ (col & 7)); }

__global__ __launch_bounds__(256, 4) void fused_line_mlp_fb(
    const unsigned short* __restrict__ ldescT, const float* __restrict__ enc,
    const int* __restrict__ jx,
    const unsigned short* __restrict__ W1s, const unsigned short* __restrict__ W2s,
    const float* __restrict__ c1, const float* __restrict__ b2,
    unsigned short* __restrict__ U) {
  __shared__ uint4 smem4[64 * 32];
  unsigned short* sm = (unsigned short*)smem4;
  const int b = blockIdx.y;
  const int e0 = blockIdx.x * 64;
  const int t = threadIdx.x;
  {
    int j = t >> 2, p = t & 3;
    int i0 = jx[(size_t)b * Ee + e0 + j];
    const uint4* s0 = (const uint4*)(ldescT + ((size_t)b * Nn + i0) * Dd + p * 32);
#pragma unroll
    for (int q = 0; q < 4; ++q) smem4[swz(j, p * 4 + q)] = s0[q];
  }
  {
    int j = t & 63, dg = t >> 6;
    const float* src = enc + ((size_t)b * Dd + dg * 32) * Ee + e0 + j;
#pragma unroll
    for (int i8 = 0; i8 < 4; ++i8) {
      uint4 pk;
      unsigned int* pw = (unsigned int*)&pk;
#pragma unroll
      for (int d2 = 0; d2 < 4; ++d2) {
        float f0 = src[(size_t)(i8 * 8 + d2 * 2) * Ee];
        float f1 = src[(size_t)(i8 * 8 + d2 * 2 + 1) * Ee];
        pw[d2] = (unsigned int)f2bf(f0) | ((unsigned int)f2bf(f1) << 16);
      }
      smem4[swz(j, 16 + dg * 4 + i8)] = pk;
    }
  }
  __syncthreads();
  const int w = t >> 6, lr = t & 15, lk = (t & 63) >> 4;
  f32x4 acc[4][4] = {};
#pragma unroll
  for (int ks = 0; ks < 12; ++ks) {
    s16x8 bfrag[4];
#pragma unroll
    for (int ct = 0; ct < 4; ++ct) {
      int c = ct * 16 + lr;
      int ce, bu;
      if (ks < 4)      { ce = c;     bu = ks * 4 + lk; }
      else if (ks < 8) { ce = c ^ 1; bu = (ks - 4) * 4 + lk; }
      else             { ce = c;     bu = 16 + (ks - 8) * 4 + lk; }
      bfrag[ct] = *(const s16x8*)&sm[swz(ce, bu) * 8];
    }
#pragma unroll
    for (int rt = 0; rt < 4; ++rt) {
      const s16x8 afrag = *(const s16x8*)&W1s[(size_t)(w * 64 + rt * 16 + lr) * 384 + ks * 32 + lk * 8];
#pragma unroll
      for (int ct = 0; ct < 4; ++ct)
        acc[rt][ct] = __builtin_amdgcn_mfma_f32_16x16x32_bf16(afrag, bfrag[ct], acc[rt][ct], 0, 0, 0);
    }
  }
  __syncthreads();
#pragma unroll
  for (int rt = 0; rt < 4; ++rt) {
    int rowbase = w * 64 + rt * 16 + lk * 4;
    int unit = rowbase >> 3, inner = rowbase & 7;
    float c1v[4];
#pragma unroll
    for (int r = 0; r < 4; ++r) c1v[r] = c1[rowbase + r];
#pragma unroll
    for (int ct = 0; ct < 4; ++ct) {
      int col = ct * 16 + lr;
      float v0 = fmaxf(acc[rt][ct][0] + c1v[0], 0.f);
      float v1 = fmaxf(acc[rt][ct][1] + c1v[1], 0.f);
      float v2 = fmaxf(acc[rt][ct][2] + c1v[2], 0.f);
      float v3 = fmaxf(acc[rt][ct][3] + c1v[3], 0.f);
      uint2 pk;
      pk.x = (unsigned int)f2bf(v0) | ((unsigned int)f2bf(v1) << 16);
      pk.y = (unsigned int)f2bf(v2) | ((unsigned int)f2bf(v3) << 16);
      *(uint2*)&sm[swz(col, unit) * 8 + inner] = pk;
    }
  }
  __syncthreads();
  f32x4 acc2[2][4] = {};
#pragma unroll
  for (int ks = 0; ks < 8; ++ks) {
    s16x8 bfrag[4];
#pragma unroll
    for (int ct = 0; ct < 4; ++ct) {
      int c = ct * 16 + lr;
      bfrag[ct] = *(const s16x8*)&sm[swz(c, ks * 4 + lk) * 8];
    }
#pragma unroll
    for (int rt = 0; rt < 2; ++rt) {
      const s16x8 afrag = *(const s16x8*)&W2s[(size_t)(w * 32 + rt * 16 + lr) * 256 + ks * 32 + lk * 8];
#pragma unroll
      for (int ct = 0; ct < 4; ++ct)
        acc2[rt][ct] = __builtin_amdgcn_mfma_f32_16x16x32_bf16(afrag, bfrag[ct], acc2[rt][ct], 0, 0, 0);
    }
  }
#pragma unroll
  for (int rt = 0; rt < 2; ++rt) {
    int rowbase = w * 32 + rt * 16 + lk * 4;
    float b2v[4];
#pragma unroll
    for (int r = 0; r < 4; ++r) b2v[r] = b2[rowbase + r];
#pragma unroll
    for (int ct = 0; ct < 4; ++ct) {
      int col = ct * 16 + lr;
      float v0 = acc2[rt][ct][0] + b2v[0];
      float v1 = acc2[rt][ct][1] + b2v[1];
      float v2 = acc2[rt][ct][2] + b2v[2];
      float v3 = acc2[rt][ct][3] + b2v[3];
      uint2 pk;
      pk.x = (unsigned int)f2bf(v0) | ((unsigned int)f2bf(v1) << 16);
      pk.y = (unsigned int)f2bf(v2) | ((unsigned int)f2bf(v3) << 16);
      *(uint2*)&U[(((size_t)b * Ee + e0 + col) << 7) + rowbase] = pk;
    }
  }
}

// ---- scatter-mean + residual + transpose (R3-proven serial-chain version) ----
__global__ __launch_bounds__(256) void scatter_finalize(
    const unsigned short* __restrict__ U, const int* __restrict__ elist_s,
    const int* __restrict__ offs_s, const float* __restrict__ ldesc_s,
    float* __restrict__ out_s) {
  __shared__ float lsum[64][129];
  const int b = blockIdx.y;
  const int n0 = blockIdx.x * 64;
  const int t = threadIdx.x;
  const int w = t >> 6, lane = t & 63;
  const unsigned int* Uu = (const unsigned int*)U;

#pragma unroll 1
  for (int q = 0; q < 16; ++q) {
    int jj = w * 16 + q;
    int n = n0 + jj;
    int s = offs_s[b * Nn + n];
    int e_end = (n == Nn - 1) ? Ee : offs_s[b * Nn + n + 1];
    float s0 = 0.f, s1 = 0.f;
    for (int k = s; k < e_end; ++k) {
      int e = elist_s[(size_t)b * Ee + k];
      unsigned int p = Uu[(((size_t)b * Ee + e) << 6) + lane];
      union { unsigned int u; float f; } lo, hi;
      lo.u = p << 16;
      hi.u = p & 0xffff0000u;
      s0 += lo.f;
      s1 += hi.f;
    }
    float inv = (e_end > s) ? 1.0f / (float)(e_end - s) : 0.0f;
    lsum[jj][lane * 2] = s0 * inv;
    lsum[jj][lane * 2 + 1] = s1 * inv;
  }
  __syncthreads();

  int nloc = t & 63;
  int dbase = (t >> 6) * 32;
#pragma unroll
  for (int i = 0; i < 32; ++i) {
    int d = dbase + i;
    size_t o = (size_t)(b * Dd + d) * Nn + n0 + nloc;
    out_s[o] = ldesc_s[o] + lsum[nloc][d];
  }
}

extern "C" void kernel_launch(void* const* d_in, const int* in_sizes, int n_in,
                              void* d_out, int out_size, void* d_ws, size_t ws_size,
                              hipStream_t stream) {
  const float* ldesc0 = (const float*)d_in[0];
  const float* ldesc1 = (const float*)d_in[1];
  const float* enc0   = (const float*)d_in[2];
  const float* enc1   = (const float*)d_in[3];
  const int*   idx0   = (const int*)d_in[4];
  const int*   idx1   = (const int*)d_in[5];
  const float* w1     = (const float*)d_in[6];
  const float* b1     = (const float*)d_in[7];
  const float* g      = (const float*)d_in[8];
  const float* beta   = (const float*)d_in[9];
  const float* mu     = (const float*)d_in[10];
  const float* var    = (const float*)d_in[11];
  const float* w2     = (const float*)d_in[12];
  const float* b2     = (const float*)d_in[13];
  float* out = (float*)d_out;

  char* ws = (char*)d_ws;
  size_t off = 0;
  unsigned short* t   = (unsigned short*)(ws + off); off += (size_t)Bb * Nn * Dd * 2;
  unsigned short* W1s = (unsigned short*)(ws + off); off += 256 * 384 * 2;
  unsigned short* W2s = (unsigned short*)(ws + off); off += 128 * 256 * 2;
  float* c1   = (float*)(ws + off); off += 256 * 4;
  int* hist   = (int*)(ws + off); off += (size_t)8 * Nn * 4;
  int* offs   = (int*)(ws + off); off += (size_t)8 * Nn * 4;
  int* cursor = (int*)(ws + off); off += (size_t)8 * Nn * 4;
  int* elist  = (int*)(ws + off); off += (size_t)8 * Ee * 4;
  unsigned short* U = (unsigned short*)(ws + off); off += (size_t)Bb * Ee * Dd * 2;
  unsigned short* encT = (unsigned short*)(ws + off);
  size_t need_new = off + (size_t)Bb * Ee * Dd * 2;

  hipMemsetAsync(hist, 0, (size_t)8 * Nn * 4, stream);
  prep_weights<<<384, 256, 0, stream>>>(w1, b1, g, beta, mu, var, w2, W1s, W2s, c1);
  hist_kernel<<<2048, 256, 0, stream>>>(idx0, idx1, hist);
  scan_kernel<<<8, 1024, 0, stream>>>(hist, offs, cursor);
  fill_kernel<<<2048, 256, 0, stream>>>(idx0, idx1, cursor, elist);

  const bool use_new = (ws_size >= need_new);

  for (int side = 0; side < 2; ++side) {
    const float* ldesc_s = side ? ldesc1 : ldesc0;
    const float* enc_s = side ? enc1 : enc0;
    const int* jx = side ? idx1 : idx0;
    transpose_f2b<<<dim3(Nn / 32, Dd / 32, Bb), dim3(32, 8), 0, stream>>>(ldesc_s, t, Nn);
    if (use_new) {
      transpose_f2b<<<dim3(Ee / 32, Dd / 32, Bb), dim3(32, 8), 0, stream>>>(enc_s, encT, Ee);
      fused_mlp_ws<<<256, 512, 0, stream>>>(t, encT, jx, W1s, W2s, c1, b2, U);
    } else {
      fused_line_mlp_fb<<<dim3(Ee / 64, Bb), 256, 0, stream>>>(t, enc_s, jx, W1s, W2s, c1, b2, U);
    }
    scatter_finalize<<<dim3(Nn / 64, Bb), 256, 0, stream>>>(
        U, elist + (size_t)side * 4 * Ee, offs + (size_t)side * 4 * Nn,
        ldesc_s, out + (size_t)side * Bb * Dd * Nn);
  }
}